// Round 6
// baseline (38.595 us; speedup 1.0000x reference)
//
#include <hip/hip_runtime.h>
#include <cstdint>
#include <cmath>

#define EPS_F 1e-8f

constexpr int B = 8, H = 8, CELLS = 8192, W = 256;
constexpr int W4 = 64;             // float4 per W-row
constexpr int TC = 32;             // cells per block
constexpr int NBLK = CELLS / TC;   // 256 blocks per (b,h) row

// ws float layout:
//   [0, 32768)        T:   [b][lane 0..63][16 f4]  per-lane kq/q table
//                          lane = h'*16 + ws ; f4 idx = j*4 + hh*2 + dn
//                          dn=0: kq[h'+4hh][16j+ws], dn=1: m2[h'+4hh][16j+ws]
//   [32768, 32896)    cb:  [b][h] float2 {kn, beta}
//   [32896, +32768)   part:[b*H][NBLK] float2 {max, sumexp}
constexpr int OFF_CB   = 32768;
constexpr int OFF_PART = 32896;

// ---- DPP rotate-add reduction over a row of 16 lanes (pure VALU) ----------
template <int CTRL>
__device__ __forceinline__ float ror_add(float v) {
    int x = __builtin_amdgcn_update_dpp(0, __builtin_bit_cast(int, v),
                                        CTRL, 0xf, 0xf, false);
    return v + __builtin_bit_cast(float, x);
}
__device__ __forceinline__ float row_sum16(float v) {
    v = ror_add<0x121>(v);   // row_ror:1
    v = ror_add<0x122>(v);   // row_ror:2
    v = ror_add<0x124>(v);   // row_ror:4
    v = ror_add<0x128>(v);   // row_ror:8
    return v;                // every lane holds the 16-lane sum
}

// ---------------------------------------------------------------------------
// Kernel P: per (b,h): scatter kq/m2 into the per-lane table layout; kn+beta.
// grid = 64 blocks x 256 threads (t = w).
// ---------------------------------------------------------------------------
__global__ __launch_bounds__(256) void ca_prep(
    const float* __restrict__ keys, const float* __restrict__ mask,
    const float* __restrict__ betas, float* __restrict__ ws)
{
    const int bh = blockIdx.x;        // b*8 + h
    const int b = bh >> 3, h = bh & 7;
    const int t = threadIdx.x;        // w
    float k = keys[bh * W + t];
    float m = mask[bh * W + t];       // MASK_MIN = 0 -> mask unchanged
    float m2 = m * m;
    float kq = k * m2;

    const int w4 = t >> 2, e = t & 3;
    const int j = w4 >> 4, wsl = w4 & 15;
    const int hp = h & 3, hh = h >> 2;
    size_t base = ((((size_t)b * 64 + hp * 16 + wsl) * 16) + j * 4 + hh * 2) * 4 + e;
    ws[base]     = kq;     // dn = 0
    ws[base + 4] = m2;     // dn = 1 (next f4)

    float km = k * m;
    float v = km * km;
#pragma unroll
    for (int s = 32; s; s >>= 1) v += __shfl_xor(v, s, 64);
    __shared__ float red[4];
    const int lane = t & 63, wv = t >> 6;
    if (lane == 0) red[wv] = v;
    __syncthreads();
    if (t == 0) {
        float kn = sqrtf((red[0] + red[1]) + (red[2] + red[3]));
        ((float2*)(ws + OFF_CB))[bh] = make_float2(kn, betas[bh]);
    }
}

// ---------------------------------------------------------------------------
// Kernel A: scores + softmax partials.
// grid = (NBLK, B) = (256, 8), 256 threads (4 waves), 3 blocks/CU.
// lane = h'*16 + ws (h' in 0..3, ws in 0..15); lane covers heads h' and h'+4.
// Per cell: 4 full-width ds_read_b128 (whole 1KB row once), kq/q from VGPRs,
// ws-reduction via DPP row_ror.
// ---------------------------------------------------------------------------
__global__ __launch_bounds__(256, 3) void ca_scores(
    const float4* __restrict__ mem4,   // [B*CELLS][W4]
    const float* __restrict__ ws,
    float* __restrict__ out,           // [B*H][CELLS]
    float2* __restrict__ part)         // [B*H][NBLK]
{
    __shared__ float4 s_tile[TC * W4];   // 32 KB, natural layout
    __shared__ float  s_sc[H][TC + 1];   // score transpose buffer
    __shared__ float  s_fin[H], s_sum2[H];

    const int b = blockIdx.y, blk = blockIdx.x, t = threadIdx.x;
    const int c0 = blk * TC;
    const int lane = t & 63, wv = t >> 6;
    const int hp  = (lane >> 4) & 3;     // h'
    const int wsl = lane & 15;           // ws slot

    // ---- staging loads first (HBM burst, oldest in vmcnt FIFO) ----
    const float4* __restrict__ gbase = mem4 + ((size_t)b * CELLS + c0) * W4;
    float4 st[8];
#pragma unroll
    for (int i = 0; i < 8; ++i) st[i] = gbase[t + i * 256];

    // ---- per-lane table + coef loads (L2-hot, overlap with staging) ----
    const float4* __restrict__ tbase = (const float4*)ws + ((size_t)b * 64 + lane) * 16;
    float4 tb[16];
#pragma unroll
    for (int i = 0; i < 16; ++i) tb[i] = tbase[i];
    const float2* __restrict__ cbp = (const float2*)(ws + OFF_CB) + b * H;
    float2 cbA = cbp[hp];        // {kn, beta} head h'
    float2 cbB = cbp[hp + 4];    // head h'+4

    // ---- stage to LDS (natural), barrier ----
#pragma unroll
    for (int i = 0; i < 8; ++i) s_tile[t + i * 256] = st[i];
    __syncthreads();

    // ---- main loop: 8 cells per wave ----
#pragma unroll
    for (int c = 0; c < 8; ++c) {
        const int cell = wv * 8 + c;
        const float4* __restrict__ pr = s_tile + cell * W4 + wsl;
        float4 a0 = pr[0], a1 = pr[16], a2 = pr[32], a3 = pr[48];

        float4 dA = make_float4(0.f, 0.f, 0.f, 0.f);
        float4 nA = make_float4(0.f, 0.f, 0.f, 0.f);
        float4 dB = make_float4(0.f, 0.f, 0.f, 0.f);
        float4 nB = make_float4(0.f, 0.f, 0.f, 0.f);

#define ACC(a, j)                                                           \
        {                                                                   \
            float4 sq = make_float4(a.x * a.x, a.y * a.y, a.z * a.z, a.w * a.w); \
            float4 kqA = tb[(j) * 4 + 0], qA = tb[(j) * 4 + 1];             \
            float4 kqB = tb[(j) * 4 + 2], qB = tb[(j) * 4 + 3];             \
            dA.x = fmaf(a.x, kqA.x, dA.x); dA.y = fmaf(a.y, kqA.y, dA.y);   \
            dA.z = fmaf(a.z, kqA.z, dA.z); dA.w = fmaf(a.w, kqA.w, dA.w);   \
            nA.x = fmaf(sq.x, qA.x, nA.x); nA.y = fmaf(sq.y, qA.y, nA.y);   \
            nA.z = fmaf(sq.z, qA.z, nA.z); nA.w = fmaf(sq.w, qA.w, nA.w);   \
            dB.x = fmaf(a.x, kqB.x, dB.x); dB.y = fmaf(a.y, kqB.y, dB.y);   \
            dB.z = fmaf(a.z, kqB.z, dB.z); dB.w = fmaf(a.w, kqB.w, dB.w);   \
            nB.x = fmaf(sq.x, qB.x, nB.x); nB.y = fmaf(sq.y, qB.y, nB.y);   \
            nB.z = fmaf(sq.z, qB.z, nB.z); nB.w = fmaf(sq.w, qB.w, nB.w);   \
        }
        ACC(a0, 0) ACC(a1, 1) ACC(a2, 2) ACC(a3, 3)
#undef ACC

        float d0 = (dA.x + dA.y) + (dA.z + dA.w);
        float n0 = (nA.x + nA.y) + (nA.z + nA.w);
        float d1 = (dB.x + dB.y) + (dB.z + dB.w);
        float n1 = (nB.x + nB.y) + (nB.z + nB.w);
        d0 = row_sum16(d0); n0 = row_sum16(n0);
        d1 = row_sum16(d1); n1 = row_sum16(n1);

        float s0 = d0 * cbA.y / (cbA.x * sqrtf(n0) + EPS_F);
        float s1 = d1 * cbB.y / (cbB.x * sqrtf(n1) + EPS_F);
        if (wsl == c) {                 // 4 lanes (h'=0..3) write 8 heads
            s_sc[hp][cell]     = s0;
            s_sc[hp + 4][cell] = s1;
        }
    }
    __syncthreads();

    // ---- epilogue: coalesced store + per-head block max/sumexp ----
    const int oh = t >> 5, oc = t & 31;   // 32-thread group per head
    float sc = s_sc[oh][oc];
    out[((size_t)(b * H + oh)) * CELLS + c0 + oc] = sc;

    float mx = sc;
#pragma unroll
    for (int s = 1; s <= 16; s <<= 1) mx = fmaxf(mx, __shfl_xor(mx, s, 64));
    float e = expf(sc - mx);
#pragma unroll
    for (int s = 1; s <= 16; s <<= 1) e += __shfl_xor(e, s, 64);
    if (oc == 0) { s_fin[oh] = mx; s_sum2[oh] = e; }
    __syncthreads();
    if (t < H)
        part[((size_t)(b * H + t)) * NBLK + blk] = make_float2(s_fin[t], s_sum2[t]);
}

// ---------------------------------------------------------------------------
// Kernel B: combine 256 partials per row (butterfly) + normalize.
// grid = 512 (8 per row), 256 threads, 1 float4 per thread.
// ---------------------------------------------------------------------------
__global__ __launch_bounds__(256) void ca_norm(
    float* __restrict__ out, const float2* __restrict__ part)
{
    const int row = blockIdx.x >> 3;     // b*H + h
    const int seg = blockIdx.x & 7;
    const int t = threadIdx.x, lane = t & 63;

    const float2* __restrict__ pp = part + (size_t)row * NBLK;
    float2 a0 = pp[lane], a1 = pp[lane + 64], a2 = pp[lane + 128], a3 = pp[lane + 192];
    float gm = fmaxf(fmaxf(a0.x, a1.x), fmaxf(a2.x, a3.x));
#pragma unroll
    for (int s = 32; s; s >>= 1) gm = fmaxf(gm, __shfl_xor(gm, s, 64));
    float gs = a0.y * expf(a0.x - gm) + a1.y * expf(a1.x - gm)
             + a2.y * expf(a2.x - gm) + a3.y * expf(a3.x - gm);
#pragma unroll
    for (int s = 32; s; s >>= 1) gs += __shfl_xor(gs, s, 64);
    float inv = 1.0f / gs;

    float4* p = (float4*)(out + (size_t)row * CELLS) + seg * 256;
    float4 vv = p[t];
    vv.x = expf(vv.x - gm) * inv;
    vv.y = expf(vv.y - gm) * inv;
    vv.z = expf(vv.z - gm) * inv;
    vv.w = expf(vv.w - gm) * inv;
    p[t] = vv;
}

// ---------------------------------------------------------------------------
extern "C" void kernel_launch(void* const* d_in, const int* in_sizes, int n_in,
                              void* d_out, int out_size, void* d_ws, size_t ws_size,
                              hipStream_t stream) {
    (void)in_sizes; (void)n_in; (void)out_size; (void)ws_size;
    const float* memory = (const float*)d_in[0];
    const float* keys   = (const float*)d_in[1];
    const float* betas  = (const float*)d_in[2];
    const float* mask   = (const float*)d_in[3];
    float* out = (float*)d_out;
    float* ws  = (float*)d_ws;
    float2* part = (float2*)(ws + OFF_PART);

    ca_prep<<<B * H, 256, 0, stream>>>(keys, mask, betas, ws);
    dim3 gA(NBLK, B);
    ca_scores<<<gA, 256, 0, stream>>>((const float4*)memory, ws, out, part);
    ca_norm<<<8 * B * H, 256, 0, stream>>>(out, part);
}

// Round 7
// 31.560 us; speedup vs baseline: 1.2229x; 1.2229x over previous
//
#include <hip/hip_runtime.h>
#include <cstdint>
#include <cmath>

#define EPS_F 1e-8f

constexpr int B = 8, H = 8, CELLS = 8192, W = 256;
constexpr int W4 = 64;             // float4 per W-row
constexpr int TC = 32;             // cells per block
constexpr int NBLK = CELLS / TC;   // 256 blocks per (b,h) row

// ---- DPP rotate-add reduction over a row of 16 lanes (pure VALU) ----------
template <int CTRL>
__device__ __forceinline__ float ror_add(float v) {
    int x = __builtin_amdgcn_update_dpp(0, __builtin_bit_cast(int, v),
                                        CTRL, 0xf, 0xf, false);
    return v + __builtin_bit_cast(float, x);
}
__device__ __forceinline__ float row_sum16(float v) {
    v = ror_add<0x121>(v);   // row_ror:1
    v = ror_add<0x122>(v);   // row_ror:2
    v = ror_add<0x124>(v);   // row_ror:4
    v = ror_add<0x128>(v);   // row_ror:8
    return v;                // every lane holds the 16-lane sum
}

// ---- async global->LDS DMA, 16B per lane ----------------------------------
#define GLOAD_LDS16(g, l)                                                    \
    __builtin_amdgcn_global_load_lds(                                        \
        (__attribute__((address_space(1))) void*)(void*)(g),                 \
        (__attribute__((address_space(3))) void*)(l), 16, 0, 0)

// ---------------------------------------------------------------------------
// Kernel A: fused prep + scores + softmax partials.
// grid = (NBLK, B) = (256, 8), 256 threads (4 waves), 3 blocks/CU.
// lane = hp*16 + wsl (hp 0..3, wsl 0..15); lane covers heads hp and hp+4 on
// W-slots {wsl, wsl+16, wsl+32, wsl+48}. kq/m2 table lives in 16 f4 VGPRs.
// Memory tile staged via global_load_lds (no register hold). Per cell:
// 4 ds_read_b128 (16-distinct-addr broadcast), DPP row-reduction.
// ---------------------------------------------------------------------------
__global__ __launch_bounds__(256, 3) void ca_scores(
    const float4* __restrict__ mem4,    // [B*CELLS][W4]
    const float4* __restrict__ keys4,   // [B*H][W4]
    const float4* __restrict__ mask4,   // [B*H][W4]
    const float* __restrict__ betas,    // [B*H]
    float* __restrict__ out,            // [B*H][CELLS]
    float2* __restrict__ part)          // [B*H][NBLK] (max, sumexp)
{
    __shared__ float4 s_tile[TC * W4];   // 32 KB, natural layout
    __shared__ float  s_sc[H][TC + 1];   // score transpose buffer
    __shared__ float  s_fin[H], s_sum2[H];

    const int b = blockIdx.y, blk = blockIdx.x, t = threadIdx.x;
    const int c0 = blk * TC;
    const int lane = t & 63, wv = t >> 6;
    const int hp  = (lane >> 4) & 3;     // h'
    const int wsl = lane & 15;           // W-slot within quarter

    // ---- prep loads FIRST (oldest in vmcnt FIFO -> usable at vmcnt(8)) ----
    const float4* __restrict__ kA = keys4 + ((size_t)(b * 8 + hp)) * W4;
    const float4* __restrict__ mA = mask4 + ((size_t)(b * 8 + hp)) * W4;
    const float4* __restrict__ kB = keys4 + ((size_t)(b * 8 + hp + 4)) * W4;
    const float4* __restrict__ mB = mask4 + ((size_t)(b * 8 + hp + 4)) * W4;
    float4 ka[4], ma[4], kb[4], mb[4];
#pragma unroll
    for (int j = 0; j < 4; ++j) {
        ka[j] = kA[j * 16 + wsl];  ma[j] = mA[j * 16 + wsl];
        kb[j] = kB[j * 16 + wsl];  mb[j] = mB[j * 16 + wsl];
    }
    const float beA = betas[b * 8 + hp];
    const float beB = betas[b * 8 + hp + 4];

    // ---- stage memory tile: async DMA, no VGPR hold ----
    const float4* __restrict__ gbase = mem4 + ((size_t)b * CELLS + c0) * W4;
#pragma unroll
    for (int i = 0; i < 8; ++i)
        GLOAD_LDS16(gbase + t + i * 256, &s_tile[t + i * 256]);

    // ---- build per-lane kq/m2 table + keys_norm (MASK_MIN = 0) ----
    float4 tb[16];
    float pA = 0.f, pB = 0.f;
#pragma unroll
    for (int j = 0; j < 4; ++j) {
        float4 m = ma[j];
        float4 q = make_float4(m.x * m.x, m.y * m.y, m.z * m.z, m.w * m.w);
        float4 k = ka[j];
        tb[j * 4 + 0] = make_float4(k.x * q.x, k.y * q.y, k.z * q.z, k.w * q.w);
        tb[j * 4 + 1] = q;
        float km;
        km = k.x * m.x; pA = fmaf(km, km, pA);
        km = k.y * m.y; pA = fmaf(km, km, pA);
        km = k.z * m.z; pA = fmaf(km, km, pA);
        km = k.w * m.w; pA = fmaf(km, km, pA);
        m = mb[j];
        q = make_float4(m.x * m.x, m.y * m.y, m.z * m.z, m.w * m.w);
        k = kb[j];
        tb[j * 4 + 2] = make_float4(k.x * q.x, k.y * q.y, k.z * q.z, k.w * q.w);
        tb[j * 4 + 3] = q;
        km = k.x * m.x; pB = fmaf(km, km, pB);
        km = k.y * m.y; pB = fmaf(km, km, pB);
        km = k.z * m.z; pB = fmaf(km, km, pB);
        km = k.w * m.w; pB = fmaf(km, km, pB);
    }
    const float knA = sqrtf(row_sum16(pA));
    const float knB = sqrtf(row_sum16(pB));

    __syncthreads();   // drains DMA (vmcnt 0) + barrier

    // ---- main loop: 8 cells per wave ----
#pragma unroll
    for (int c = 0; c < 8; ++c) {
        const int cell = wv * 8 + c;
        const float4* __restrict__ pr = s_tile + cell * W4 + wsl;
        float4 a0 = pr[0], a1 = pr[16], a2 = pr[32], a3 = pr[48];

        float4 dA = make_float4(0.f, 0.f, 0.f, 0.f);
        float4 nA = make_float4(0.f, 0.f, 0.f, 0.f);
        float4 dB = make_float4(0.f, 0.f, 0.f, 0.f);
        float4 nB = make_float4(0.f, 0.f, 0.f, 0.f);

#define ACC(a, j)                                                           \
        {                                                                   \
            float4 sq = make_float4(a.x * a.x, a.y * a.y, a.z * a.z, a.w * a.w); \
            float4 kqA = tb[(j) * 4 + 0], qA = tb[(j) * 4 + 1];             \
            float4 kqB = tb[(j) * 4 + 2], qB = tb[(j) * 4 + 3];             \
            dA.x = fmaf(a.x, kqA.x, dA.x); dA.y = fmaf(a.y, kqA.y, dA.y);   \
            dA.z = fmaf(a.z, kqA.z, dA.z); dA.w = fmaf(a.w, kqA.w, dA.w);   \
            nA.x = fmaf(sq.x, qA.x, nA.x); nA.y = fmaf(sq.y, qA.y, nA.y);   \
            nA.z = fmaf(sq.z, qA.z, nA.z); nA.w = fmaf(sq.w, qA.w, nA.w);   \
            dB.x = fmaf(a.x, kqB.x, dB.x); dB.y = fmaf(a.y, kqB.y, dB.y);   \
            dB.z = fmaf(a.z, kqB.z, dB.z); dB.w = fmaf(a.w, kqB.w, dB.w);   \
            nB.x = fmaf(sq.x, qB.x, nB.x); nB.y = fmaf(sq.y, qB.y, nB.y);   \
            nB.z = fmaf(sq.z, qB.z, nB.z); nB.w = fmaf(sq.w, qB.w, nB.w);   \
        }
        ACC(a0, 0) ACC(a1, 1) ACC(a2, 2) ACC(a3, 3)
#undef ACC

        float d0 = (dA.x + dA.y) + (dA.z + dA.w);
        float n0 = (nA.x + nA.y) + (nA.z + nA.w);
        float d1 = (dB.x + dB.y) + (dB.z + dB.w);
        float n1 = (nB.x + nB.y) + (nB.z + nB.w);
        d0 = row_sum16(d0); n0 = row_sum16(n0);
        d1 = row_sum16(d1); n1 = row_sum16(n1);

        float s0 = d0 * beA / (knA * sqrtf(n0) + EPS_F);
        float s1 = d1 * beB / (knB * sqrtf(n1) + EPS_F);
        if (wsl == c) {                 // 4 lanes (hp=0..3) write 8 heads
            s_sc[hp][cell]     = s0;
            s_sc[hp + 4][cell] = s1;
        }
    }
    __syncthreads();

    // ---- epilogue: coalesced store + per-head block max/sumexp ----
    const int oh = t >> 5, oc = t & 31;   // 32-thread group per head
    float sc = s_sc[oh][oc];
    out[((size_t)(b * H + oh)) * CELLS + c0 + oc] = sc;

    float mx = sc;
#pragma unroll
    for (int s = 1; s <= 16; s <<= 1) mx = fmaxf(mx, __shfl_xor(mx, s, 64));
    float e = expf(sc - mx);
#pragma unroll
    for (int s = 1; s <= 16; s <<= 1) e += __shfl_xor(e, s, 64);
    if (oc == 0) { s_fin[oh] = mx; s_sum2[oh] = e; }
    __syncthreads();
    if (t < H)
        part[((size_t)(b * H + t)) * NBLK + blk] = make_float2(s_fin[t], s_sum2[t]);
}

// ---------------------------------------------------------------------------
// Kernel B: combine 256 partials per row (butterfly) + normalize.
// grid = 512 (8 per row), 256 threads, 1 float4 per thread.
// ---------------------------------------------------------------------------
__global__ __launch_bounds__(256) void ca_norm(
    float* __restrict__ out, const float2* __restrict__ part)
{
    const int row = blockIdx.x >> 3;     // b*H + h
    const int seg = blockIdx.x & 7;
    const int t = threadIdx.x, lane = t & 63;

    const float2* __restrict__ pp = part + (size_t)row * NBLK;
    float2 a0 = pp[lane], a1 = pp[lane + 64], a2 = pp[lane + 128], a3 = pp[lane + 192];
    float gm = fmaxf(fmaxf(a0.x, a1.x), fmaxf(a2.x, a3.x));
#pragma unroll
    for (int s = 32; s; s >>= 1) gm = fmaxf(gm, __shfl_xor(gm, s, 64));
    float gs = a0.y * expf(a0.x - gm) + a1.y * expf(a1.x - gm)
             + a2.y * expf(a2.x - gm) + a3.y * expf(a3.x - gm);
#pragma unroll
    for (int s = 32; s; s >>= 1) gs += __shfl_xor(gs, s, 64);
    float inv = 1.0f / gs;

    float4* p = (float4*)(out + (size_t)row * CELLS) + seg * 256;
    float4 vv = p[t];
    vv.x = expf(vv.x - gm) * inv;
    vv.y = expf(vv.y - gm) * inv;
    vv.z = expf(vv.z - gm) * inv;
    vv.w = expf(vv.w - gm) * inv;
    p[t] = vv;
}

// ---------------------------------------------------------------------------
extern "C" void kernel_launch(void* const* d_in, const int* in_sizes, int n_in,
                              void* d_out, int out_size, void* d_ws, size_t ws_size,
                              hipStream_t stream) {
    (void)in_sizes; (void)n_in; (void)out_size; (void)ws_size;
    const float* memory = (const float*)d_in[0];
    const float* keys   = (const float*)d_in[1];
    const float* betas  = (const float*)d_in[2];
    const float* mask   = (const float*)d_in[3];
    float* out = (float*)d_out;
    float2* part = (float2*)d_ws;

    dim3 gA(NBLK, B);
    ca_scores<<<gA, 256, 0, stream>>>((const float4*)memory,
                                      (const float4*)keys, (const float4*)mask,
                                      betas, out, part);
    ca_norm<<<8 * B * H, 256, 0, stream>>>(out, part);
}